// Round 2
// baseline (148.562 us; speedup 1.0000x reference)
//
#include <hip/hip_runtime.h>
#include <math.h>

#define T_STEPS 2048
#define NU 512
#define NCH 8192      // B*U independent chains
#define PF 32         // register-ring prefetch depth (steps)

// Output layout (verified from harness behavior: complex64 ref output is cast
// to float32, dropping imag): d_out = [Re(z): T*NCH][r_f: NCH][phi_f: NCH].
//
// phi is tracked in REVOLUTIONS (f32, wrapped to [0,1) by v_fract each step)
// for the sin/cos feedback -> per-step rounding ~6e-8 rad. Full-phase f64
// accumulator (off the critical path) produces phi_f.
__global__ __launch_bounds__(64)
void reshopf_kernel(const float* __restrict__ Xr, const float* __restrict__ Xi,
                    const float* __restrict__ r0, const float* __restrict__ phi0,
                    const float* __restrict__ omegas,
                    float* __restrict__ zr, float* __restrict__ r_f,
                    float* __restrict__ phi_f)
{
    const int g = blockIdx.x * 64 + threadIdx.x;   // chain id = b*512+u
    const int u = g & (NU - 1);

    const float TWO_PI = 6.28318530717958647692f;
    const float INV2PI = 0.15915494309189533577f;

    // omega squash (f32 sigmoid: ~1e-7 rel err -> ~3e-4 rad total, negligible)
    const float wo  = omegas[u];
    const float sig = 1.0f / (1.0f + __expf(-wo));
    const float omdt     = (sig * 19.5f + 0.5f) * TWO_PI * 0.01f;  // rad/step
    const float omdt_rev = omdt * INV2PI;                          // rev/step

    float  r        = r0[g];
    const float p0  = phi0[g];
    double phi_full = (double)p0;
    float  phi_rev  = p0 * INV2PI;                 // in [0, ~0.16)
    float  s = __builtin_amdgcn_sinf(phi_rev);     // sin(phi)
    float  c = __builtin_amdgcn_cosf(phi_rev);     // cos(phi)

    // register prefetch ring: PF steps in flight (64 x 256B loads per wave)
    float pxr[PF], pxi[PF];
    const float* pr = Xr + g;
    const float* pi = Xi + g;
#pragma unroll
    for (int j = 0; j < PF; ++j) {
        pxr[j] = pr[(size_t)j * NCH];
        pxi[j] = pi[(size_t)j * NCH];
    }
    float* pz = zr + g;

    auto step = [&](int t, float xr, float xi) {
        // phi += (om - 5*xi*sin(phi)) * DT
        const float cxi      = xi * -0.05f;            // -INPUT_SCALER*DT*xi
        const float dphi_rad = fmaf(cxi, s, omdt);
        const float dphi_rev = fmaf(cxi * INV2PI, s, omdt_rev);
        phi_rev = __builtin_amdgcn_fractf(phi_rev + dphi_rev);

        // r += ((1 - r^2)*r + 5*xr*cos(phi)) * DT
        const float rr = r * r;
        const float g1 = fmaf(-rr, r, r);               // (1-r^2)*r
        r = fmaf(0.01f, g1, fmaf(0.05f * xr, c, r));

        // sincos of NEW phi: feeds Re(z) now, feedback next step
        s = __builtin_amdgcn_sinf(phi_rev);
        c = __builtin_amdgcn_cosf(phi_rev);
        phi_full += (double)dphi_rad;                   // off critical path

        __builtin_nontemporal_store(r * c, &pz[(size_t)t * NCH]);
    };

    // main chunks: prefetch unconditional
    for (int t0 = 0; t0 < T_STEPS - PF; t0 += PF) {
#pragma unroll
        for (int j = 0; j < PF; ++j) {
            const float xr = pxr[j];
            const float xi = pxi[j];
            pxr[j] = pr[(size_t)(t0 + PF + j) * NCH];
            pxi[j] = pi[(size_t)(t0 + PF + j) * NCH];
            step(t0 + j, xr, xi);
        }
    }
    // final chunk: no prefetch
#pragma unroll
    for (int j = 0; j < PF; ++j) {
        step(T_STEPS - PF + j, pxr[j], pxi[j]);
    }

    r_f[g]   = r;
    phi_f[g] = (float)phi_full;
}

extern "C" void kernel_launch(void* const* d_in, const int* in_sizes, int n_in,
                              void* d_out, int out_size, void* d_ws, size_t ws_size,
                              hipStream_t stream) {
    const float* Xr   = (const float*)d_in[0];
    const float* Xi   = (const float*)d_in[1];
    const float* r0   = (const float*)d_in[2];
    const float* phi0 = (const float*)d_in[3];
    const float* om   = (const float*)d_in[4];

    float* out   = (float*)d_out;
    float* zr    = out;                                   // Re(z): T*NCH floats
    float* r_f   = out + (size_t)T_STEPS * NCH;           // NCH floats
    float* phi_f = r_f + NCH;                             // NCH floats

    reshopf_kernel<<<NCH / 64, 64, 0, stream>>>(Xr, Xi, r0, phi0, om, zr, r_f, phi_f);
}